// Round 1
// baseline (733.986 us; speedup 1.0000x reference)
//
#include <hip/hip_runtime.h>
#include <hip/hip_bf16.h>
#include <math.h>

#define N_NODES 50000
#define N_EDGES 1600000
#define DIM 128
#define HEADS 8
#define HEAD_DIM 16

// ---------------------------------------------------------------------------
// linear128: out[n][c] = sum_k in[n][k] * W[c][k] + b[c]   (torch Linear)
// Block: 256 threads, tile = 64 rows x 128 cols, K=128 in 4 chunks of 32.
// A tile in LDS as [k][node] with XOR swizzle (conflict-free float4 reads).
// W chunk transposed into LDS as [kk][col].
// ---------------------------------------------------------------------------
__global__ __launch_bounds__(256) void linear128(
    const float* __restrict__ in, const float* __restrict__ W,
    const float* __restrict__ bias, float* __restrict__ out, int nrows) {
  __shared__ float xs[128][64];  // [k][node^swz(k)]
  __shared__ float wt[32][128];  // [kk][col]

  const int tid = threadIdx.x;
  const int nb = blockIdx.x * 64;
  const int tx = tid & 15;   // col group: cols [8*tx, 8*tx+8)
  const int ty = tid >> 4;   // row group: rows [4*ty, 4*ty+4)

  // stage x tile (8192 floats, 32 per thread), coalesced reads
  for (int it = 0; it < 32; ++it) {
    int idx = it * 256 + tid;
    int k = idx & 127;
    int node = idx >> 7;
    int row = nb + node;
    float val = (row < nrows) ? in[(size_t)row * 128 + k] : 0.0f;
    xs[k][node ^ ((k & 7) << 3)] = val;
  }

  float acc[4][8];
#pragma unroll
  for (int j = 0; j < 4; ++j)
#pragma unroll
    for (int e = 0; e < 8; ++e) acc[j][e] = 0.0f;

  const int wcol = tid >> 1;   // 0..127
  const int half = tid & 1;    // 0..1

  for (int kc = 0; kc < 4; ++kc) {
    __syncthreads();  // xs ready (kc=0) / prev wt reads done
    // stage W chunk [128 cols][32 k] -> wt[kk][col]
    const float* wrow = W + (size_t)wcol * 128 + kc * 32 + half * 16;
#pragma unroll
    for (int f = 0; f < 4; ++f) {
      float4 w4 = *(const float4*)(wrow + 4 * f);
      wt[half * 16 + 4 * f + 0][wcol] = w4.x;
      wt[half * 16 + 4 * f + 1][wcol] = w4.y;
      wt[half * 16 + 4 * f + 2][wcol] = w4.z;
      wt[half * 16 + 4 * f + 3][wcol] = w4.w;
    }
    __syncthreads();

#pragma unroll
    for (int kk = 0; kk < 32; ++kk) {
      int k = kc * 32 + kk;
      const float4 a = *(const float4*)&xs[k][(ty * 4) ^ ((k & 7) << 3)];
      const float4 b0 = *(const float4*)&wt[kk][tx * 8];
      const float4 b1 = *(const float4*)&wt[kk][tx * 8 + 4];
      float av[4] = {a.x, a.y, a.z, a.w};
      float bv[8] = {b0.x, b0.y, b0.z, b0.w, b1.x, b1.y, b1.z, b1.w};
#pragma unroll
      for (int j = 0; j < 4; ++j)
#pragma unroll
        for (int e = 0; e < 8; ++e) acc[j][e] += av[j] * bv[e];
    }
  }

  const float4 bv0 = *(const float4*)&bias[tx * 8];
  const float4 bv1 = *(const float4*)&bias[tx * 8 + 4];
#pragma unroll
  for (int j = 0; j < 4; ++j) {
    int row = nb + ty * 4 + j;
    if (row < nrows) {
      float4 o0 = {acc[j][0] + bv0.x, acc[j][1] + bv0.y,
                   acc[j][2] + bv0.z, acc[j][3] + bv0.w};
      float4 o1 = {acc[j][4] + bv1.x, acc[j][5] + bv1.y,
                   acc[j][6] + bv1.z, acc[j][7] + bv1.w};
      *(float4*)&out[(size_t)row * 128 + tx * 8] = o0;
      *(float4*)&out[(size_t)row * 128 + tx * 8 + 4] = o1;
    }
  }
}

// ---------------------------------------------------------------------------
// Counting sort of edges by dst
// ---------------------------------------------------------------------------
__global__ void hist_kernel(const int* __restrict__ dst, int* __restrict__ counts) {
  int e = blockIdx.x * 256 + threadIdx.x;
  if (e < N_EDGES) atomicAdd(&counts[dst[e]], 1);
}

__global__ __launch_bounds__(1024) void scan_kernel(
    const int* __restrict__ counts, int* __restrict__ offsets,
    int* __restrict__ cursor) {
  __shared__ int sd[1024];
  const int tid = threadIdx.x;
  const int base = tid * 49;  // 1024*49 = 50176 >= 50000
  int c[49];
  int tot = 0;
#pragma unroll
  for (int i = 0; i < 49; ++i) {
    int idx = base + i;
    c[i] = (idx < N_NODES) ? counts[idx] : 0;
    tot += c[i];
  }
  sd[tid] = tot;
  __syncthreads();
  for (int d = 1; d < 1024; d <<= 1) {
    int t = (tid >= d) ? sd[tid - d] : 0;
    __syncthreads();
    sd[tid] += t;
    __syncthreads();
  }
  int excl = sd[tid] - tot;  // exclusive prefix for this thread's chunk
#pragma unroll
  for (int i = 0; i < 49; ++i) {
    int idx = base + i;
    if (idx < N_NODES) {
      offsets[idx] = excl;
      cursor[idx] = excl;
    }
    excl += c[i];
  }
  if (tid == 1023) offsets[N_NODES] = excl;  // == N_EDGES
}

__global__ void scatter_kernel(const int* __restrict__ src,
                               const int* __restrict__ dst,
                               int* __restrict__ cursor,
                               int* __restrict__ ssrc) {
  int e = blockIdx.x * 256 + threadIdx.x;
  if (e < N_EDGES) {
    int d = dst[e];
    int pos = atomicAdd(&cursor[d], 1);
    ssrc[pos] = src[e];
  }
}

// ---------------------------------------------------------------------------
// edge_agg: one wave per dst node, online softmax over incoming edges,
// all 8 heads in parallel. lane -> dims [2*lane, 2*lane+1], head = lane/8.
// Writes agg[n][d] = (sum_e exp(s_e - m) * v[src_e][d]) / z  (already normed)
// ---------------------------------------------------------------------------
__global__ __launch_bounds__(256) void edge_agg_kernel(
    const float* __restrict__ q, const float* __restrict__ kbuf,
    const float* __restrict__ v, const int* __restrict__ offsets,
    const int* __restrict__ ssrc, float* __restrict__ agg) {
  const int wid = threadIdx.x >> 6;
  const int lane = threadIdx.x & 63;
  const int n = blockIdx.x * 4 + wid;
  if (n >= N_NODES) return;

  const float2 kn = *(const float2*)(kbuf + (size_t)n * 128 + lane * 2);
  const int start = offsets[n];
  const int end = offsets[n + 1];

  float m = -INFINITY, zz = 0.0f, a0 = 0.0f, a1 = 0.0f;
  for (int e = start; e < end; ++e) {
    int s = ssrc[e];
    const float2 qv = *(const float2*)(q + (size_t)s * 128 + lane * 2);
    const float2 vv = *(const float2*)(v + (size_t)s * 128 + lane * 2);
    float p = qv.x * kn.x + qv.y * kn.y;
    p += __shfl_xor(p, 1);
    p += __shfl_xor(p, 2);
    p += __shfl_xor(p, 4);           // per-head dot over 16 dims (8 lanes)
    float sc = p * 0.25f;            // / sqrt(16)
    float mn = fmaxf(m, sc);
    float r = __expf(m - mn);        // exp(-inf)=0 on first iter
    float pe = __expf(sc - mn);
    zz = zz * r + pe;
    a0 = a0 * r + pe * vv.x;
    a1 = a1 * r + pe * vv.y;
    m = mn;
  }
  float inv = (zz > 0.0f) ? 1.0f / zz : 0.0f;  // zero-degree node -> agg = 0
  float2 o = {a0 * inv, a1 * inv};
  *(float2*)(agg + (size_t)n * 128 + lane * 2) = o;
}

// ---------------------------------------------------------------------------
extern "C" void kernel_launch(void* const* d_in, const int* in_sizes, int n_in,
                              void* d_out, int out_size, void* d_ws, size_t ws_size,
                              hipStream_t stream) {
  const float* x  = (const float*)d_in[0];
  const int* src  = (const int*)d_in[1];
  const int* dst  = (const int*)d_in[2];
  const float* Wq = (const float*)d_in[3];
  const float* bq = (const float*)d_in[4];
  const float* Wk = (const float*)d_in[5];
  const float* bk = (const float*)d_in[6];
  const float* Wv = (const float*)d_in[7];
  const float* bv = (const float*)d_in[8];
  const float* Wo = (const float*)d_in[9];
  const float* bo = (const float*)d_in[10];
  float* out = (float*)d_out;

  // workspace carve-up (256B aligned regions)
  char* ws = (char*)d_ws;
  size_t off = 0;
  auto carve = [&](size_t bytes) {
    size_t r = off;
    off = (off + bytes + 255) & ~(size_t)255;
    return r;
  };
  const size_t mat_bytes = (size_t)N_NODES * 128 * sizeof(float);
  float* q    = (float*)(ws + carve(mat_bytes));
  float* kbuf = (float*)(ws + carve(mat_bytes));
  float* vbuf = (float*)(ws + carve(mat_bytes));
  float* agg  = (float*)(ws + carve(mat_bytes));
  int* counts  = (int*)(ws + carve((size_t)N_NODES * sizeof(int)));
  int* offsets = (int*)(ws + carve((size_t)(N_NODES + 1) * sizeof(int)));
  int* cursor  = (int*)(ws + carve((size_t)N_NODES * sizeof(int)));
  int* ssrc    = (int*)(ws + carve((size_t)N_EDGES * sizeof(int)));

  hipMemsetAsync(counts, 0, (size_t)N_NODES * sizeof(int), stream);

  const int gemm_grid = (N_NODES + 63) / 64;  // 782
  linear128<<<gemm_grid, 256, 0, stream>>>(x, Wq, bq, q, N_NODES);
  linear128<<<gemm_grid, 256, 0, stream>>>(x, Wk, bk, kbuf, N_NODES);
  linear128<<<gemm_grid, 256, 0, stream>>>(x, Wv, bv, vbuf, N_NODES);

  const int edge_grid = (N_EDGES + 255) / 256;  // 6250
  hist_kernel<<<edge_grid, 256, 0, stream>>>(dst, counts);
  scan_kernel<<<1, 1024, 0, stream>>>(counts, offsets, cursor);
  scatter_kernel<<<edge_grid, 256, 0, stream>>>(src, dst, cursor, ssrc);

  edge_agg_kernel<<<(N_NODES + 3) / 4, 256, 0, stream>>>(q, kbuf, vbuf, offsets,
                                                         ssrc, agg);

  linear128<<<gemm_grid, 256, 0, stream>>>(agg, Wo, bo, out, N_NODES);
}

// Round 2
// 555.402 us; speedup vs baseline: 1.3215x; 1.3215x over previous
//
#include <hip/hip_runtime.h>
#include <hip/hip_bf16.h>
#include <math.h>

#define N_NODES 50000
#define N_EDGES 1600000
#define DIM 128
#define HEADS 8
#define HEAD_DIM 16

static __device__ __forceinline__ unsigned short f2bf(float f) {
  unsigned int b = __float_as_uint(f);
  unsigned int r = (b + 0x7FFFu + ((b >> 16) & 1u)) >> 16;  // round-nearest-even
  return (unsigned short)r;
}
static __device__ __forceinline__ float bf2f(unsigned short u) {
  return __uint_as_float(((unsigned int)u) << 16);
}

// ---------------------------------------------------------------------------
// fused QKV: one x-tile staging, three weight passes.
//   Q -> kept in registers (acc_q)
//   K -> kbuf fp32 [n][128]
//   V -> interleaved with Q as bf16 records qv[n]: 64 x ushort4
//        entry d = { q[2d], q[2d+1], v[2d], v[2d+1] }   (512 B per node)
// Block: 256 threads, tile = 64 rows x 128 cols, K=128 in 4 chunks of 32.
// ---------------------------------------------------------------------------
__global__ __launch_bounds__(256) void qkv_fused(
    const float* __restrict__ in,
    const float* __restrict__ Wq, const float* __restrict__ bq,
    const float* __restrict__ Wk, const float* __restrict__ bk,
    const float* __restrict__ Wv, const float* __restrict__ bv,
    unsigned short* __restrict__ qv, float* __restrict__ kbuf, int nrows) {
  __shared__ float xs[128][64];  // [k][node^swz(k)]
  __shared__ float wt[32][128];  // [kk][col]

  const int tid = threadIdx.x;
  const int nb = blockIdx.x * 64;
  const int tx = tid & 15;   // col group: cols [8*tx, 8*tx+8)
  const int ty = tid >> 4;   // row group: rows [4*ty, 4*ty+4)

  for (int it = 0; it < 32; ++it) {
    int idx = it * 256 + tid;
    int k = idx & 127;
    int node = idx >> 7;
    int row = nb + node;
    float val = (row < nrows) ? in[(size_t)row * 128 + k] : 0.0f;
    xs[k][node ^ ((k & 7) << 3)] = val;
  }

  const int wcol = tid >> 1;
  const int half = tid & 1;

  float acc_q[4][8];
  float acc[4][8];

  // ---- three passes over weights; wt re-staged per chunk per pass ----
  for (int pass = 0; pass < 3; ++pass) {
    const float* W = (pass == 0) ? Wq : (pass == 1) ? Wk : Wv;
#pragma unroll
    for (int j = 0; j < 4; ++j)
#pragma unroll
      for (int e = 0; e < 8; ++e) acc[j][e] = 0.0f;

    for (int kc = 0; kc < 4; ++kc) {
      __syncthreads();  // protects wt (prev use) and xs (first iter)
      const float* wrow = W + (size_t)wcol * 128 + kc * 32 + half * 16;
#pragma unroll
      for (int f = 0; f < 4; ++f) {
        float4 w4 = *(const float4*)(wrow + 4 * f);
        wt[half * 16 + 4 * f + 0][wcol] = w4.x;
        wt[half * 16 + 4 * f + 1][wcol] = w4.y;
        wt[half * 16 + 4 * f + 2][wcol] = w4.z;
        wt[half * 16 + 4 * f + 3][wcol] = w4.w;
      }
      __syncthreads();

#pragma unroll
      for (int kk = 0; kk < 32; ++kk) {
        int k = kc * 32 + kk;
        const float4 a = *(const float4*)&xs[k][(ty * 4) ^ ((k & 7) << 3)];
        const float4 b0 = *(const float4*)&wt[kk][tx * 8];
        const float4 b1 = *(const float4*)&wt[kk][tx * 8 + 4];
        float av[4] = {a.x, a.y, a.z, a.w};
        float bw[8] = {b0.x, b0.y, b0.z, b0.w, b1.x, b1.y, b1.z, b1.w};
#pragma unroll
        for (int j = 0; j < 4; ++j)
#pragma unroll
          for (int e = 0; e < 8; ++e) acc[j][e] += av[j] * bw[e];
      }
    }

    if (pass == 0) {
      // stash Q (+bias) in registers
      const float4 b0 = *(const float4*)&bq[tx * 8];
      const float4 b1 = *(const float4*)&bq[tx * 8 + 4];
      float bb[8] = {b0.x, b0.y, b0.z, b0.w, b1.x, b1.y, b1.z, b1.w};
#pragma unroll
      for (int j = 0; j < 4; ++j)
#pragma unroll
        for (int e = 0; e < 8; ++e) acc_q[j][e] = acc[j][e] + bb[e];
    } else if (pass == 1) {
      // store K fp32
      const float4 b0 = *(const float4*)&bk[tx * 8];
      const float4 b1 = *(const float4*)&bk[tx * 8 + 4];
#pragma unroll
      for (int j = 0; j < 4; ++j) {
        int row = nb + ty * 4 + j;
        if (row < nrows) {
          float4 o0 = {acc[j][0] + b0.x, acc[j][1] + b0.y,
                       acc[j][2] + b0.z, acc[j][3] + b0.w};
          float4 o1 = {acc[j][4] + b1.x, acc[j][5] + b1.y,
                       acc[j][6] + b1.z, acc[j][7] + b1.w};
          *(float4*)&kbuf[(size_t)row * 128 + tx * 8] = o0;
          *(float4*)&kbuf[(size_t)row * 128 + tx * 8 + 4] = o1;
        }
      }
    } else {
      // V: interleave with stashed Q as bf16 records
      const float4 b0 = *(const float4*)&bv[tx * 8];
      const float4 b1 = *(const float4*)&bv[tx * 8 + 4];
      float bb[8] = {b0.x, b0.y, b0.z, b0.w, b1.x, b1.y, b1.z, b1.w};
#pragma unroll
      for (int j = 0; j < 4; ++j) {
        int row = nb + ty * 4 + j;
        if (row < nrows) {
          unsigned short u[16];
#pragma unroll
          for (int p = 0; p < 4; ++p) {
            u[4 * p + 0] = f2bf(acc_q[j][2 * p]);
            u[4 * p + 1] = f2bf(acc_q[j][2 * p + 1]);
            u[4 * p + 2] = f2bf(acc[j][2 * p] + bb[2 * p]);
            u[4 * p + 3] = f2bf(acc[j][2 * p + 1] + bb[2 * p + 1]);
          }
          unsigned short* dstp = qv + (size_t)row * 256 + tx * 16;
          *(uint4*)(dstp) = *(const uint4*)&u[0];
          *(uint4*)(dstp + 8) = *(const uint4*)&u[8];
        }
      }
    }
  }
}

// ---------------------------------------------------------------------------
// linear128 (used for the output projection): out = in @ W^T + b
// ---------------------------------------------------------------------------
__global__ __launch_bounds__(256) void linear128(
    const float* __restrict__ in, const float* __restrict__ W,
    const float* __restrict__ bias, float* __restrict__ out, int nrows) {
  __shared__ float xs[128][64];
  __shared__ float wt[32][128];

  const int tid = threadIdx.x;
  const int nb = blockIdx.x * 64;
  const int tx = tid & 15;
  const int ty = tid >> 4;

  for (int it = 0; it < 32; ++it) {
    int idx = it * 256 + tid;
    int k = idx & 127;
    int node = idx >> 7;
    int row = nb + node;
    float val = (row < nrows) ? in[(size_t)row * 128 + k] : 0.0f;
    xs[k][node ^ ((k & 7) << 3)] = val;
  }

  float acc[4][8];
#pragma unroll
  for (int j = 0; j < 4; ++j)
#pragma unroll
    for (int e = 0; e < 8; ++e) acc[j][e] = 0.0f;

  const int wcol = tid >> 1;
  const int half = tid & 1;

  for (int kc = 0; kc < 4; ++kc) {
    __syncthreads();
    const float* wrow = W + (size_t)wcol * 128 + kc * 32 + half * 16;
#pragma unroll
    for (int f = 0; f < 4; ++f) {
      float4 w4 = *(const float4*)(wrow + 4 * f);
      wt[half * 16 + 4 * f + 0][wcol] = w4.x;
      wt[half * 16 + 4 * f + 1][wcol] = w4.y;
      wt[half * 16 + 4 * f + 2][wcol] = w4.z;
      wt[half * 16 + 4 * f + 3][wcol] = w4.w;
    }
    __syncthreads();

#pragma unroll
    for (int kk = 0; kk < 32; ++kk) {
      int k = kc * 32 + kk;
      const float4 a = *(const float4*)&xs[k][(ty * 4) ^ ((k & 7) << 3)];
      const float4 b0 = *(const float4*)&wt[kk][tx * 8];
      const float4 b1 = *(const float4*)&wt[kk][tx * 8 + 4];
      float av[4] = {a.x, a.y, a.z, a.w};
      float bw[8] = {b0.x, b0.y, b0.z, b0.w, b1.x, b1.y, b1.z, b1.w};
#pragma unroll
      for (int j = 0; j < 4; ++j)
#pragma unroll
        for (int e = 0; e < 8; ++e) acc[j][e] += av[j] * bw[e];
    }
  }

  const float4 bv0 = *(const float4*)&bias[tx * 8];
  const float4 bv1 = *(const float4*)&bias[tx * 8 + 4];
#pragma unroll
  for (int j = 0; j < 4; ++j) {
    int row = nb + ty * 4 + j;
    if (row < nrows) {
      float4 o0 = {acc[j][0] + bv0.x, acc[j][1] + bv0.y,
                   acc[j][2] + bv0.z, acc[j][3] + bv0.w};
      float4 o1 = {acc[j][4] + bv1.x, acc[j][5] + bv1.y,
                   acc[j][6] + bv1.z, acc[j][7] + bv1.w};
      *(float4*)&out[(size_t)row * 128 + tx * 8] = o0;
      *(float4*)&out[(size_t)row * 128 + tx * 8 + 4] = o1;
    }
  }
}

// ---------------------------------------------------------------------------
// Counting sort of edges by dst
// ---------------------------------------------------------------------------
__global__ void hist_kernel(const int* __restrict__ dst, int* __restrict__ counts) {
  int e = blockIdx.x * 256 + threadIdx.x;
  if (e < N_EDGES) atomicAdd(&counts[dst[e]], 1);
}

__global__ __launch_bounds__(1024) void scan_kernel(
    const int* __restrict__ counts, int* __restrict__ offsets,
    int* __restrict__ cursor) {
  __shared__ int sd[1024];
  const int tid = threadIdx.x;
  const int base = tid * 49;  // 1024*49 = 50176 >= 50000
  int c[49];
  int tot = 0;
#pragma unroll
  for (int i = 0; i < 49; ++i) {
    int idx = base + i;
    c[i] = (idx < N_NODES) ? counts[idx] : 0;
    tot += c[i];
  }
  sd[tid] = tot;
  __syncthreads();
  for (int d = 1; d < 1024; d <<= 1) {
    int t = (tid >= d) ? sd[tid - d] : 0;
    __syncthreads();
    sd[tid] += t;
    __syncthreads();
  }
  int excl = sd[tid] - tot;
#pragma unroll
  for (int i = 0; i < 49; ++i) {
    int idx = base + i;
    if (idx < N_NODES) {
      offsets[idx] = excl;
      cursor[idx] = excl;
    }
    excl += c[i];
  }
  if (tid == 1023) offsets[N_NODES] = excl;
}

__global__ void scatter_kernel(const int* __restrict__ src,
                               const int* __restrict__ dst,
                               int* __restrict__ cursor,
                               int* __restrict__ ssrc) {
  int e = blockIdx.x * 256 + threadIdx.x;
  if (e < N_EDGES) {
    int d = dst[e];
    int pos = atomicAdd(&cursor[d], 1);
    ssrc[pos] = src[e];
  }
}

// ---------------------------------------------------------------------------
// edge_agg: one wave per dst node, online softmax over incoming edges.
// lane -> dims [2*lane, 2*lane+1], head = lane/8 (8 lanes per head).
// Gathers the interleaved bf16 qv record: one ushort4 (8 B) per lane per edge.
// ---------------------------------------------------------------------------
__global__ __launch_bounds__(256) void edge_agg_kernel(
    const unsigned short* __restrict__ qv, const float* __restrict__ kbuf,
    const int* __restrict__ offsets, const int* __restrict__ ssrc,
    float* __restrict__ agg) {
  const int wid = threadIdx.x >> 6;
  const int lane = threadIdx.x & 63;
  const int n = blockIdx.x * 4 + wid;
  if (n >= N_NODES) return;

  const float2 kn = *(const float2*)(kbuf + (size_t)n * 128 + lane * 2);
  const int start = offsets[n];
  const int end = offsets[n + 1];

  float m = -INFINITY, zz = 0.0f, a0 = 0.0f, a1 = 0.0f;
  int e = start;
  for (; e + 1 < end; e += 2) {
    int s0 = ssrc[e];
    int s1 = ssrc[e + 1];
    const ushort4 t0 = *(const ushort4*)(qv + ((size_t)s0 << 8) + lane * 4);
    const ushort4 t1 = *(const ushort4*)(qv + ((size_t)s1 << 8) + lane * 4);
    float p0 = bf2f(t0.x) * kn.x + bf2f(t0.y) * kn.y;
    float p1 = bf2f(t1.x) * kn.x + bf2f(t1.y) * kn.y;
    p0 += __shfl_xor(p0, 1);  p1 += __shfl_xor(p1, 1);
    p0 += __shfl_xor(p0, 2);  p1 += __shfl_xor(p1, 2);
    p0 += __shfl_xor(p0, 4);  p1 += __shfl_xor(p1, 4);
    float sc0 = p0 * 0.25f;
    float sc1 = p1 * 0.25f;
    float mn = fmaxf(m, fmaxf(sc0, sc1));
    float r = __expf(m - mn);
    float e0 = __expf(sc0 - mn);
    float e1 = __expf(sc1 - mn);
    zz = zz * r + e0 + e1;
    a0 = a0 * r + e0 * bf2f(t0.z) + e1 * bf2f(t1.z);
    a1 = a1 * r + e0 * bf2f(t0.w) + e1 * bf2f(t1.w);
    m = mn;
  }
  if (e < end) {
    int s0 = ssrc[e];
    const ushort4 t0 = *(const ushort4*)(qv + ((size_t)s0 << 8) + lane * 4);
    float p0 = bf2f(t0.x) * kn.x + bf2f(t0.y) * kn.y;
    p0 += __shfl_xor(p0, 1);
    p0 += __shfl_xor(p0, 2);
    p0 += __shfl_xor(p0, 4);
    float sc0 = p0 * 0.25f;
    float mn = fmaxf(m, sc0);
    float r = __expf(m - mn);
    float e0 = __expf(sc0 - mn);
    zz = zz * r + e0;
    a0 = a0 * r + e0 * bf2f(t0.z);
    a1 = a1 * r + e0 * bf2f(t0.w);
  }
  float inv = (zz > 0.0f) ? 1.0f / zz : 0.0f;
  float2 o = {a0 * inv, a1 * inv};
  *(float2*)(agg + (size_t)n * 128 + lane * 2) = o;
}

// ---------------------------------------------------------------------------
extern "C" void kernel_launch(void* const* d_in, const int* in_sizes, int n_in,
                              void* d_out, int out_size, void* d_ws, size_t ws_size,
                              hipStream_t stream) {
  const float* x  = (const float*)d_in[0];
  const int* src  = (const int*)d_in[1];
  const int* dst  = (const int*)d_in[2];
  const float* Wq = (const float*)d_in[3];
  const float* bq = (const float*)d_in[4];
  const float* Wk = (const float*)d_in[5];
  const float* bk = (const float*)d_in[6];
  const float* Wv = (const float*)d_in[7];
  const float* bv = (const float*)d_in[8];
  const float* Wo = (const float*)d_in[9];
  const float* bo = (const float*)d_in[10];
  float* out = (float*)d_out;

  char* ws = (char*)d_ws;
  size_t off = 0;
  auto carve = [&](size_t bytes) {
    size_t r = off;
    off = (off + bytes + 255) & ~(size_t)255;
    return r;
  };
  const size_t mat_bytes = (size_t)N_NODES * 128 * sizeof(float);
  unsigned short* qv = (unsigned short*)(ws + carve((size_t)N_NODES * 512));
  float* kbuf = (float*)(ws + carve(mat_bytes));
  float* agg  = (float*)(ws + carve(mat_bytes));
  int* counts  = (int*)(ws + carve((size_t)N_NODES * sizeof(int)));
  int* offsets = (int*)(ws + carve((size_t)(N_NODES + 1) * sizeof(int)));
  int* cursor  = (int*)(ws + carve((size_t)N_NODES * sizeof(int)));
  int* ssrc    = (int*)(ws + carve((size_t)N_EDGES * sizeof(int)));

  hipMemsetAsync(counts, 0, (size_t)N_NODES * sizeof(int), stream);

  const int gemm_grid = (N_NODES + 63) / 64;  // 782
  qkv_fused<<<gemm_grid, 256, 0, stream>>>(x, Wq, bq, Wk, bk, Wv, bv, qv, kbuf,
                                           N_NODES);

  const int edge_grid = (N_EDGES + 255) / 256;  // 6250
  hist_kernel<<<edge_grid, 256, 0, stream>>>(dst, counts);
  scan_kernel<<<1, 1024, 0, stream>>>(counts, offsets, cursor);
  scatter_kernel<<<edge_grid, 256, 0, stream>>>(src, dst, cursor, ssrc);

  edge_agg_kernel<<<(N_NODES + 3) / 4, 256, 0, stream>>>(qv, kbuf, offsets,
                                                         ssrc, agg);

  linear128<<<gemm_grid, 256, 0, stream>>>(agg, Wo, bo, out, N_NODES);
}

// Round 3
// 339.980 us; speedup vs baseline: 2.1589x; 1.6336x over previous
//
#include <hip/hip_runtime.h>
#include <hip/hip_bf16.h>
#include <math.h>

#define N_NODES 50000
#define N_EDGES 1600000
#define DIM 128
#define HEADS 8
#define HEAD_DIM 16
#define NBUCK 256                    // coarse buckets = dst>>8; 196 active
#define NBUCK_ACTIVE ((N_NODES + 255) / 256)   // 196
#define P1_BLOCKS ((N_EDGES + 4095) / 4096)    // 391

static __device__ __forceinline__ unsigned short f2bf(float f) {
  unsigned int b = __float_as_uint(f);
  unsigned int r = (b + 0x7FFFu + ((b >> 16) & 1u)) >> 16;  // RNE
  return (unsigned short)r;
}
static __device__ __forceinline__ float bf2f(unsigned short u) {
  return __uint_as_float(((unsigned int)u) << 16);
}
// padded-swizzled wt layout: row stride 144 floats, +4 floats per 32-col group
// -> ds_read_b128 of cols tx*8 is 2-way (free) instead of 4-way
static __device__ __forceinline__ int wt_off(int kk, int col) {
  return kk * 144 + col + ((col >> 5) << 2);
}

// ---------------------------------------------------------------------------
// fused QKV: one x-tile staging, three weight passes.
//   Q -> registers; K -> kbuf fp32; V -> interleaved with Q as bf16 qv records
//   qv[n]: 64 x ushort4 { q[2d], q[2d+1], v[2d], v[2d+1] }  (512 B/node)
// ---------------------------------------------------------------------------
__global__ __launch_bounds__(256) void qkv_fused(
    const float* __restrict__ in,
    const float* __restrict__ Wq, const float* __restrict__ bq,
    const float* __restrict__ Wk, const float* __restrict__ bk,
    const float* __restrict__ Wv, const float* __restrict__ bv,
    unsigned short* __restrict__ qv, float* __restrict__ kbuf, int nrows) {
  __shared__ float xs[128][64];   // [k][node^swz(k)]
  __shared__ float wt[32 * 144];  // padded-swizzled [kk][col]

  const int tid = threadIdx.x;
  const int nb = blockIdx.x * 64;
  const int tx = tid & 15;
  const int ty = tid >> 4;

  for (int it = 0; it < 32; ++it) {
    int idx = it * 256 + tid;
    int k = idx & 127;
    int node = idx >> 7;
    int row = nb + node;
    float val = (row < nrows) ? in[(size_t)row * 128 + k] : 0.0f;
    xs[k][node ^ ((k & 7) << 3)] = val;
  }

  const int wcol = tid >> 1;
  const int half = tid & 1;

  float acc_q[4][8];
  float acc[4][8];

  for (int pass = 0; pass < 3; ++pass) {
    const float* W = (pass == 0) ? Wq : (pass == 1) ? Wk : Wv;
#pragma unroll
    for (int j = 0; j < 4; ++j)
#pragma unroll
      for (int e = 0; e < 8; ++e) acc[j][e] = 0.0f;

    for (int kc = 0; kc < 4; ++kc) {
      __syncthreads();
      const float* wrow = W + (size_t)wcol * 128 + kc * 32 + half * 16;
#pragma unroll
      for (int f = 0; f < 4; ++f) {
        float4 w4 = *(const float4*)(wrow + 4 * f);
        wt[wt_off(half * 16 + 4 * f + 0, wcol)] = w4.x;
        wt[wt_off(half * 16 + 4 * f + 1, wcol)] = w4.y;
        wt[wt_off(half * 16 + 4 * f + 2, wcol)] = w4.z;
        wt[wt_off(half * 16 + 4 * f + 3, wcol)] = w4.w;
      }
      __syncthreads();

#pragma unroll
      for (int kk = 0; kk < 32; ++kk) {
        int k = kc * 32 + kk;
        const float4 a = *(const float4*)&xs[k][(ty * 4) ^ ((k & 7) << 3)];
        const float4 b0 = *(const float4*)&wt[wt_off(kk, tx * 8)];
        const float4 b1 = *(const float4*)&wt[wt_off(kk, tx * 8 + 4)];
        float av[4] = {a.x, a.y, a.z, a.w};
        float bw[8] = {b0.x, b0.y, b0.z, b0.w, b1.x, b1.y, b1.z, b1.w};
#pragma unroll
        for (int j = 0; j < 4; ++j)
#pragma unroll
          for (int e = 0; e < 8; ++e) acc[j][e] += av[j] * bw[e];
      }
    }

    if (pass == 0) {
      const float4 b0 = *(const float4*)&bq[tx * 8];
      const float4 b1 = *(const float4*)&bq[tx * 8 + 4];
      float bb[8] = {b0.x, b0.y, b0.z, b0.w, b1.x, b1.y, b1.z, b1.w};
#pragma unroll
      for (int j = 0; j < 4; ++j)
#pragma unroll
        for (int e = 0; e < 8; ++e) acc_q[j][e] = acc[j][e] + bb[e];
    } else if (pass == 1) {
      const float4 b0 = *(const float4*)&bk[tx * 8];
      const float4 b1 = *(const float4*)&bk[tx * 8 + 4];
#pragma unroll
      for (int j = 0; j < 4; ++j) {
        int row = nb + ty * 4 + j;
        if (row < nrows) {
          float4 o0 = {acc[j][0] + b0.x, acc[j][1] + b0.y,
                       acc[j][2] + b0.z, acc[j][3] + b0.w};
          float4 o1 = {acc[j][4] + b1.x, acc[j][5] + b1.y,
                       acc[j][6] + b1.z, acc[j][7] + b1.w};
          *(float4*)&kbuf[(size_t)row * 128 + tx * 8] = o0;
          *(float4*)&kbuf[(size_t)row * 128 + tx * 8 + 4] = o1;
        }
      }
    } else {
      const float4 b0 = *(const float4*)&bv[tx * 8];
      const float4 b1 = *(const float4*)&bv[tx * 8 + 4];
      float bb[8] = {b0.x, b0.y, b0.z, b0.w, b1.x, b1.y, b1.z, b1.w};
#pragma unroll
      for (int j = 0; j < 4; ++j) {
        int row = nb + ty * 4 + j;
        if (row < nrows) {
          unsigned short u[16];
#pragma unroll
          for (int p = 0; p < 4; ++p) {
            u[4 * p + 0] = f2bf(acc_q[j][2 * p]);
            u[4 * p + 1] = f2bf(acc_q[j][2 * p + 1]);
            u[4 * p + 2] = f2bf(acc[j][2 * p] + bb[2 * p]);
            u[4 * p + 3] = f2bf(acc[j][2 * p + 1] + bb[2 * p + 1]);
          }
          unsigned short* dstp = qv + (size_t)row * 256 + tx * 16;
          *(uint4*)(dstp) = *(const uint4*)&u[0];
          *(uint4*)(dstp + 8) = *(const uint4*)&u[8];
        }
      }
    }
  }
}

// ---------------------------------------------------------------------------
// output projection: out = in @ W^T + b
// ---------------------------------------------------------------------------
__global__ __launch_bounds__(256) void linear128(
    const float* __restrict__ in, const float* __restrict__ W,
    const float* __restrict__ bias, float* __restrict__ out, int nrows) {
  __shared__ float xs[128][64];
  __shared__ float wt[32 * 144];

  const int tid = threadIdx.x;
  const int nb = blockIdx.x * 64;
  const int tx = tid & 15;
  const int ty = tid >> 4;

  for (int it = 0; it < 32; ++it) {
    int idx = it * 256 + tid;
    int k = idx & 127;
    int node = idx >> 7;
    int row = nb + node;
    float val = (row < nrows) ? in[(size_t)row * 128 + k] : 0.0f;
    xs[k][node ^ ((k & 7) << 3)] = val;
  }

  float acc[4][8];
#pragma unroll
  for (int j = 0; j < 4; ++j)
#pragma unroll
    for (int e = 0; e < 8; ++e) acc[j][e] = 0.0f;

  const int wcol = tid >> 1;
  const int half = tid & 1;

  for (int kc = 0; kc < 4; ++kc) {
    __syncthreads();
    const float* wrow = W + (size_t)wcol * 128 + kc * 32 + half * 16;
#pragma unroll
    for (int f = 0; f < 4; ++f) {
      float4 w4 = *(const float4*)(wrow + 4 * f);
      wt[wt_off(half * 16 + 4 * f + 0, wcol)] = w4.x;
      wt[wt_off(half * 16 + 4 * f + 1, wcol)] = w4.y;
      wt[wt_off(half * 16 + 4 * f + 2, wcol)] = w4.z;
      wt[wt_off(half * 16 + 4 * f + 3, wcol)] = w4.w;
    }
    __syncthreads();

#pragma unroll
    for (int kk = 0; kk < 32; ++kk) {
      int k = kc * 32 + kk;
      const float4 a = *(const float4*)&xs[k][(ty * 4) ^ ((k & 7) << 3)];
      const float4 b0 = *(const float4*)&wt[wt_off(kk, tx * 8)];
      const float4 b1 = *(const float4*)&wt[wt_off(kk, tx * 8 + 4)];
      float av[4] = {a.x, a.y, a.z, a.w};
      float bw[8] = {b0.x, b0.y, b0.z, b0.w, b1.x, b1.y, b1.z, b1.w};
#pragma unroll
      for (int j = 0; j < 4; ++j)
#pragma unroll
        for (int e = 0; e < 8; ++e) acc[j][e] += av[j] * bw[e];
    }
  }

  const float4 bv0 = *(const float4*)&bias[tx * 8];
  const float4 bv1 = *(const float4*)&bias[tx * 8 + 4];
#pragma unroll
  for (int j = 0; j < 4; ++j) {
    int row = nb + ty * 4 + j;
    if (row < nrows) {
      float4 o0 = {acc[j][0] + bv0.x, acc[j][1] + bv0.y,
                   acc[j][2] + bv0.z, acc[j][3] + bv0.w};
      float4 o1 = {acc[j][4] + bv1.x, acc[j][5] + bv1.y,
                   acc[j][6] + bv1.z, acc[j][7] + bv1.w};
      *(float4*)&out[(size_t)row * 128 + tx * 8] = o0;
      *(float4*)&out[(size_t)row * 128 + tx * 8 + 4] = o1;
    }
  }
}

// ---------------------------------------------------------------------------
// Hierarchical bucket sort of edges by dst (no far atomics in per-edge path).
// bucket = dst >> 8. Edges packed as (dst<<16)|src (both < 65536).
// ---------------------------------------------------------------------------
__global__ __launch_bounds__(256) void bucket_hist(const int* __restrict__ dst,
                                                   int* __restrict__ bcnt) {
  __shared__ int h[NBUCK];
  const int t = threadIdx.x;
  h[t] = 0;
  __syncthreads();
  const int base = blockIdx.x * 4096;
#pragma unroll
  for (int i = 0; i < 16; ++i) {
    int e = base + i * 256 + t;
    if (e < N_EDGES) atomicAdd(&h[dst[e] >> 8], 1);
  }
  __syncthreads();
  if (h[t]) atomicAdd(&bcnt[t], h[t]);
}

__global__ __launch_bounds__(256) void bucket_scan(const int* __restrict__ bcnt,
                                                   int* __restrict__ bbase,
                                                   int* __restrict__ bcursor) {
  __shared__ int sd[NBUCK];
  const int t = threadIdx.x;
  const int own = bcnt[t];
  sd[t] = own;
  __syncthreads();
  for (int d = 1; d < NBUCK; d <<= 1) {
    int v = (t >= d) ? sd[t - d] : 0;
    __syncthreads();
    sd[t] += v;
    __syncthreads();
  }
  int excl = sd[t] - own;
  bbase[t] = excl;
  bcursor[t] = excl;
  if (t == NBUCK - 1) bbase[NBUCK] = sd[t];
}

__global__ __launch_bounds__(256) void bucket_partition(
    const int* __restrict__ src, const int* __restrict__ dst,
    int* __restrict__ bcursor, unsigned int* __restrict__ packed) {
  __shared__ int h[NBUCK];
  __shared__ int gbase[NBUCK];
  const int t = threadIdx.x;
  h[t] = 0;
  __syncthreads();
  const int base = blockIdx.x * 4096;
  unsigned int val[16];
  int binrank[16];
#pragma unroll
  for (int i = 0; i < 16; ++i) {
    int e = base + i * 256 + t;
    if (e < N_EDGES) {
      int d = dst[e];
      val[i] = ((unsigned)d << 16) | (unsigned)src[e];
      int bin = d >> 8;
      int r = atomicAdd(&h[bin], 1);
      binrank[i] = (bin << 16) | r;
    } else {
      binrank[i] = -1;
    }
  }
  __syncthreads();
  if (h[t] > 0) gbase[t] = atomicAdd(&bcursor[t], h[t]);  // one far atomic per (block,bin)
  __syncthreads();
#pragma unroll
  for (int i = 0; i < 16; ++i) {
    if (binrank[i] >= 0) {
      int bin = binrank[i] >> 16;
      int r = binrank[i] & 0xFFFF;
      packed[gbase[bin] + r] = val[i];
    }
  }
}

__global__ __launch_bounds__(256) void bucket_finalize(
    const unsigned int* __restrict__ packed, const int* __restrict__ bbase,
    int* __restrict__ offsets, unsigned short* __restrict__ ssrc) {
  __shared__ int cnt[NBUCK];
  __shared__ int sd[NBUCK];
  __shared__ int cur[NBUCK];
  const int t = threadIdx.x;
  const int b = blockIdx.x;
  const int beg = bbase[b], end = bbase[b + 1];
  cnt[t] = 0;
  __syncthreads();
  for (int e = beg + t; e < end; e += 256)
    atomicAdd(&cnt[(packed[e] >> 16) & 255], 1);
  __syncthreads();
  const int own = cnt[t];
  sd[t] = own;
  __syncthreads();
  for (int d = 1; d < NBUCK; d <<= 1) {
    int v = (t >= d) ? sd[t - d] : 0;
    __syncthreads();
    sd[t] += v;
    __syncthreads();
  }
  const int excl = sd[t] - own;
  cur[t] = excl;
  const int node = b * 256 + t;
  if (node < N_NODES) offsets[node] = beg + excl;  // bucket-major = dst-major
  if (b == 0 && t == 0) offsets[N_NODES] = N_EDGES;
  __syncthreads();
  for (int e = beg + t; e < end; e += 256) {
    unsigned int p = packed[e];
    int local = (p >> 16) & 255;
    int r = atomicAdd(&cur[local], 1);
    ssrc[beg + r] = (unsigned short)(p & 0xFFFFu);
  }
}

// ---------------------------------------------------------------------------
// edge_agg: one wave per dst node, online softmax over its (sorted) edges.
// lane -> dims [2*lane, 2*lane+1], head = lane/8.
// ---------------------------------------------------------------------------
__global__ __launch_bounds__(256) void edge_agg_kernel(
    const unsigned short* __restrict__ qv, const float* __restrict__ kbuf,
    const int* __restrict__ offsets, const unsigned short* __restrict__ ssrc,
    float* __restrict__ agg) {
  const int wid = threadIdx.x >> 6;
  const int lane = threadIdx.x & 63;
  const int n = blockIdx.x * 4 + wid;
  if (n >= N_NODES) return;

  const float2 kn = *(const float2*)(kbuf + (size_t)n * 128 + lane * 2);
  const int start = offsets[n];
  const int end = offsets[n + 1];

  float m = -INFINITY, zz = 0.0f, a0 = 0.0f, a1 = 0.0f;
  int e = start;
  for (; e + 1 < end; e += 2) {
    int s0 = ssrc[e];
    int s1 = ssrc[e + 1];
    const ushort4 t0 = *(const ushort4*)(qv + ((size_t)s0 << 8) + lane * 4);
    const ushort4 t1 = *(const ushort4*)(qv + ((size_t)s1 << 8) + lane * 4);
    float p0 = bf2f(t0.x) * kn.x + bf2f(t0.y) * kn.y;
    float p1 = bf2f(t1.x) * kn.x + bf2f(t1.y) * kn.y;
    p0 += __shfl_xor(p0, 1);  p1 += __shfl_xor(p1, 1);
    p0 += __shfl_xor(p0, 2);  p1 += __shfl_xor(p1, 2);
    p0 += __shfl_xor(p0, 4);  p1 += __shfl_xor(p1, 4);
    float sc0 = p0 * 0.25f;
    float sc1 = p1 * 0.25f;
    float mn = fmaxf(m, fmaxf(sc0, sc1));
    float r = __expf(m - mn);
    float e0 = __expf(sc0 - mn);
    float e1 = __expf(sc1 - mn);
    zz = zz * r + e0 + e1;
    a0 = a0 * r + e0 * bf2f(t0.z) + e1 * bf2f(t1.z);
    a1 = a1 * r + e0 * bf2f(t0.w) + e1 * bf2f(t1.w);
    m = mn;
  }
  if (e < end) {
    int s0 = ssrc[e];
    const ushort4 t0 = *(const ushort4*)(qv + ((size_t)s0 << 8) + lane * 4);
    float p0 = bf2f(t0.x) * kn.x + bf2f(t0.y) * kn.y;
    p0 += __shfl_xor(p0, 1);
    p0 += __shfl_xor(p0, 2);
    p0 += __shfl_xor(p0, 4);
    float sc0 = p0 * 0.25f;
    float mn = fmaxf(m, sc0);
    float r = __expf(m - mn);
    float e0 = __expf(sc0 - mn);
    zz = zz * r + e0;
    a0 = a0 * r + e0 * bf2f(t0.z);
    a1 = a1 * r + e0 * bf2f(t0.w);
  }
  float inv = (zz > 0.0f) ? 1.0f / zz : 0.0f;
  float2 o = {a0 * inv, a1 * inv};
  *(float2*)(agg + (size_t)n * 128 + lane * 2) = o;
}

// ---------------------------------------------------------------------------
extern "C" void kernel_launch(void* const* d_in, const int* in_sizes, int n_in,
                              void* d_out, int out_size, void* d_ws, size_t ws_size,
                              hipStream_t stream) {
  const float* x  = (const float*)d_in[0];
  const int* src  = (const int*)d_in[1];
  const int* dst  = (const int*)d_in[2];
  const float* Wq = (const float*)d_in[3];
  const float* bq = (const float*)d_in[4];
  const float* Wk = (const float*)d_in[5];
  const float* bk = (const float*)d_in[6];
  const float* Wv = (const float*)d_in[7];
  const float* bv = (const float*)d_in[8];
  const float* Wo = (const float*)d_in[9];
  const float* bo = (const float*)d_in[10];
  float* out = (float*)d_out;

  char* ws = (char*)d_ws;
  size_t off = 0;
  auto carve = [&](size_t bytes) {
    size_t r = off;
    off = (off + bytes + 255) & ~(size_t)255;
    return r;
  };
  const size_t mat_bytes = (size_t)N_NODES * 128 * sizeof(float);
  unsigned short* qv = (unsigned short*)(ws + carve((size_t)N_NODES * 512));
  float* kbuf = (float*)(ws + carve(mat_bytes));
  float* agg  = (float*)(ws + carve(mat_bytes));
  unsigned int* packed = (unsigned int*)(ws + carve((size_t)N_EDGES * 4));
  unsigned short* ssrc = (unsigned short*)(ws + carve((size_t)N_EDGES * 2));
  int* offsets = (int*)(ws + carve((size_t)(N_NODES + 1) * sizeof(int)));
  int* bcnt    = (int*)(ws + carve(NBUCK * sizeof(int)));
  int* bbase   = (int*)(ws + carve((NBUCK + 1) * sizeof(int)));
  int* bcursor = (int*)(ws + carve(NBUCK * sizeof(int)));

  hipMemsetAsync(bcnt, 0, NBUCK * sizeof(int), stream);

  const int gemm_grid = (N_NODES + 63) / 64;  // 782
  qkv_fused<<<gemm_grid, 256, 0, stream>>>(x, Wq, bq, Wk, bk, Wv, bv, qv, kbuf,
                                           N_NODES);

  bucket_hist<<<P1_BLOCKS, 256, 0, stream>>>(dst, bcnt);
  bucket_scan<<<1, 256, 0, stream>>>(bcnt, bbase, bcursor);
  bucket_partition<<<P1_BLOCKS, 256, 0, stream>>>(src, dst, bcursor, packed);
  bucket_finalize<<<NBUCK_ACTIVE, 256, 0, stream>>>(packed, bbase, offsets, ssrc);

  edge_agg_kernel<<<(N_NODES + 3) / 4, 256, 0, stream>>>(qv, kbuf, offsets,
                                                         ssrc, agg);

  linear128<<<gemm_grid, 256, 0, stream>>>(agg, Wo, bo, out, N_NODES);
}